// Round 8
// baseline (72.093 us; speedup 1.0000x reference)
//
#include <hip/hip_runtime.h>
#include <stdint.h>

#define M_ROWS 8192
#define NCLUST 512
#define KDIM   2048

#define BM    32                 // rows per block
#define NSTEP (KDIM / 128)       // 16 K-steps of 128 fp8 elements

typedef __attribute__((ext_vector_type(4))) int   i32x4;
typedef __attribute__((ext_vector_type(8))) int   i32x8;
typedef __attribute__((ext_vector_type(4))) float f32x4;

__device__ __forceinline__ void gload_lds16(const void* g, void* l) {
    __builtin_amdgcn_global_load_lds(
        (const __attribute__((address_space(1))) void*)g,
        (__attribute__((address_space(3))) void*)l,
        16, 0, 0);
}

// ---------------------------------------------------------------------------
// Kernel 1: f32 -> fp8 e4m3 (HW v_cvt_pk_fp8_f32) + per-row sum of squares
// (from ORIGINAL f32 values). Rows 0..8191 = z, 8192..8703 = centroids.
// One wave per row. Zeroes colsum (required before gemm's atomics each call).
// ---------------------------------------------------------------------------
__global__ __launch_bounds__(256) void k_convert(
    const float* __restrict__ z, const float* __restrict__ cent,
    unsigned char* __restrict__ zb, unsigned char* __restrict__ cb,
    float* __restrict__ zsq, float* __restrict__ csq,
    float* __restrict__ colsum)
{
    int w = threadIdx.x >> 6, lane = threadIdx.x & 63;
    int row = blockIdx.x * 4 + w;  // 0..8703

    const float* src;
    unsigned char* dst;
    float* nrm;
    int r;
    if (row < M_ROWS) { src = z + (size_t)row * KDIM; dst = zb + (size_t)row * KDIM; nrm = zsq; r = row; }
    else              { r = row - M_ROWS; src = cent + (size_t)r * KDIM; dst = cb + (size_t)r * KDIM; nrm = csq; }

    float s = 0.f;
    #pragma unroll
    for (int it = 0; it < KDIM / 256; ++it) {
        int idx = it * 256 + lane * 4;
        float4 v = *(const float4*)(src + idx);
        s += v.x * v.x + v.y * v.y + v.z * v.z + v.w * v.w;
        int p = __builtin_amdgcn_cvt_pk_fp8_f32(v.x, v.y, 0, 0);   // bytes 0,1
        p     = __builtin_amdgcn_cvt_pk_fp8_f32(v.z, v.w, p, 1);   // bytes 2,3
        *(int*)(dst + idx) = p;
    }
    #pragma unroll
    for (int off = 32; off; off >>= 1) s += __shfl_down(s, off);
    if (lane == 0) nrm[r] = s;

    if (blockIdx.x == 0) {
        colsum[threadIdx.x] = 0.f;
        colsum[threadIdx.x + 256] = 0.f;
    }
}

// ---------------------------------------------------------------------------
// Kernel 2: fused barrier-free GEMM + Q epilogue.
// Block = 32 rows x ALL 512 cols x ALL K.  Grid 256 = 1 block/CU; 1024
// threads = 16 waves = 4 waves/SIMD.  Wave w owns cols [32w, 32w+32).
//
//  - A panel (32 x 2048B fp8, 64 KiB) staged to LDS ONCE in prologue with
//    the proven 16B-slot XOR swizzle (phys slot = logical ^ (row&7) within
//    each 128B group; pre-swizzled global source, linear LDS dest).
//    ONE barrier total; the K-loop is completely barrier-free.
//  - B fragments read per K-step DIRECTLY from global: cb is 1 MB fp8,
//    fully L2-resident per XCD.  Per-wave counted waits (compiler) replace
//    all inter-wave synchronization; 1-deep register prefetch on B.
//  - Epilogue (block owns full rows): Q_u = 1/(1+sqrt(max(zsq+csq-2c,0))),
//    in-block rowsum (shfl over 16 col-lanes + LDS over 16 waves),
//    normalized Q written to out, per-col partials atomically added to
//    colsum (each wave owns distinct cols -> 512 atomics/block).
// ---------------------------------------------------------------------------
__global__ __launch_bounds__(1024, 4) void k_gemm_fused(
    const unsigned char* __restrict__ zb, const unsigned char* __restrict__ cb,
    const float* __restrict__ zsq, const float* __restrict__ csq,
    float* __restrict__ Q, float* __restrict__ colsum)
{
    __shared__ unsigned char As[BM * KDIM];   // 64 KiB
    __shared__ float rws[BM][16];             // rowsum partials per wave
    __shared__ float rinv[BM];

    const int tid  = threadIdx.x;
    const int w    = tid >> 6, lane = tid & 63;
    const int rbase = blockIdx.x * BM;
    const int l15  = lane & 15;
    const int s    = lane >> 4;               // K 32-byte sub-block 0..3

    // ---- prologue: stage A panel; wave w stages rows 2w, 2w+1 ----
    #pragma unroll
    for (int t = 0; t < 4; ++t) {
        const int row  = 2 * w + (t >> 1);
        const int half = t & 1;
        const unsigned char* src = zb + (size_t)(rbase + row) * KDIM
            + half * 1024 + (lane >> 3) * 128 + (((lane & 7) ^ (row & 7)) * 16);
        gload_lds16(src, &As[row * KDIM + half * 1024]);
    }
    __syncthreads();   // the only barrier before the epilogue

    f32x4 acc[2][2] = {};
    const int sc = 0x7F7F7F7F;   // e8m0 scale 127 = 2^0 per byte

    // B base: wave's col block; frag col = colb + j*16 + l15
    const int colb = w * 32;
    const unsigned char* bbase = cb + (size_t)(colb + l15) * KDIM + s * 32;

    // 1-deep B prefetch (buffers indexed by k&1; loop fully unrolled ->
    // compile-time indices, rule #20 safe)
    i32x4 bl[2][2][2];
    #pragma unroll
    for (int j = 0; j < 2; ++j) {
        bl[0][j][0] = *(const i32x4*)(bbase + (size_t)j * 16 * KDIM);
        bl[0][j][1] = *(const i32x4*)(bbase + (size_t)j * 16 * KDIM + 16);
    }

    #pragma unroll
    for (int k = 0; k < NSTEP; ++k) {
        const int cur = k & 1;
        if (k + 1 < NSTEP) {
            #pragma unroll
            for (int j = 0; j < 2; ++j) {
                bl[cur ^ 1][j][0] = *(const i32x4*)(bbase + (size_t)j * 16 * KDIM + (k + 1) * 128);
                bl[cur ^ 1][j][1] = *(const i32x4*)(bbase + (size_t)j * 16 * KDIM + (k + 1) * 128 + 16);
            }
        }
        // A fragments from LDS (swizzled slots; group index == k)
        i32x8 af[2];
        #pragma unroll
        for (int i = 0; i < 2; ++i) {
            const int row = i * 16 + l15;
            const i32x4 lo = *(const i32x4*)&As[row * KDIM + k * 128 + (((2 * s)     ^ (row & 7)) * 16)];
            const i32x4 hi = *(const i32x4*)&As[row * KDIM + k * 128 + (((2 * s + 1) ^ (row & 7)) * 16)];
            af[i][0] = lo[0]; af[i][1] = lo[1]; af[i][2] = lo[2]; af[i][3] = lo[3];
            af[i][4] = hi[0]; af[i][5] = hi[1]; af[i][6] = hi[2]; af[i][7] = hi[3];
        }
        #pragma unroll
        for (int j = 0; j < 2; ++j) {
            i32x8 bf;
            bf[0] = bl[cur][j][0][0]; bf[1] = bl[cur][j][0][1];
            bf[2] = bl[cur][j][0][2]; bf[3] = bl[cur][j][0][3];
            bf[4] = bl[cur][j][1][0]; bf[5] = bl[cur][j][1][1];
            bf[6] = bl[cur][j][1][2]; bf[7] = bl[cur][j][1][3];
            #pragma unroll
            for (int i = 0; i < 2; ++i)
                acc[i][j] = __builtin_amdgcn_mfma_scale_f32_16x16x128_f8f6f4(
                    af[i], bf, acc[i][j], 0, 0, 0, sc, 0, sc);
        }
    }

    // ---- fused epilogue ----
    // C/D mapping: col = l15, row = s*4 + reg (within each 16x16 frag)
    float csv[2];
    csv[0] = csq[colb + l15];
    csv[1] = csq[colb + 16 + l15];

    float qv[2][2][4];
    #pragma unroll
    for (int i = 0; i < 2; ++i) {
        #pragma unroll
        for (int r = 0; r < 4; ++r) {
            const float zr = zsq[rbase + i * 16 + s * 4 + r];
            #pragma unroll
            for (int j = 0; j < 2; ++j) {
                const float d2 = zr + csv[j] - 2.0f * acc[i][j][r];
                qv[i][j][r] = 1.0f / (1.0f + sqrtf(fmaxf(d2, 0.0f)));
            }
        }
    }

    // rowsum: per (i,r) partial over this lane's 2 cols, reduce over l15
    #pragma unroll
    for (int i = 0; i < 2; ++i) {
        #pragma unroll
        for (int r = 0; r < 4; ++r) {
            float rp = qv[i][0][r] + qv[i][1][r];
            rp += __shfl_xor(rp, 1);
            rp += __shfl_xor(rp, 2);
            rp += __shfl_xor(rp, 4);
            rp += __shfl_xor(rp, 8);
            if (l15 == 0) rws[i * 16 + s * 4 + r][w] = rp;
        }
    }
    __syncthreads();
    if (tid < BM) {
        float ssum = 0.f;
        #pragma unroll
        for (int w2 = 0; w2 < 16; ++w2) ssum += rws[tid][w2];
        rinv[tid] = 1.0f / ssum;
    }
    __syncthreads();

    // normalize, write Q, accumulate colsum partials
    float cp0 = 0.f, cp1 = 0.f;
    #pragma unroll
    for (int i = 0; i < 2; ++i) {
        #pragma unroll
        for (int r = 0; r < 4; ++r) {
            const int row = i * 16 + s * 4 + r;
            const float ri = rinv[row];
            const size_t off = (size_t)(rbase + row) * NCLUST + colb;
            const float q0 = qv[i][0][r] * ri;
            const float q1 = qv[i][1][r] * ri;
            Q[off + l15]      = q0;
            Q[off + 16 + l15] = q1;
            cp0 += q0;
            cp1 += q1;
        }
    }
    // reduce over s (4 lanes at stride 16)
    cp0 += __shfl_xor(cp0, 16); cp0 += __shfl_xor(cp0, 32);
    cp1 += __shfl_xor(cp1, 16); cp1 += __shfl_xor(cp1, 32);
    if (s == 0) {
        atomicAdd(&colsum[colb + l15], cp0);
        atomicAdd(&colsum[colb + 16 + l15], cp1);
    }
}

// ---------------------------------------------------------------------------
// Kernel 3: P = rownorm(Q^2 / colsum). One wave per row.
// ---------------------------------------------------------------------------
__global__ __launch_bounds__(256) void k_p(
    const float* __restrict__ Q, const float* __restrict__ colsum,
    float* __restrict__ P)
{
    const int w = threadIdx.x >> 6, lane = threadIdx.x & 63;
    const int row = blockIdx.x * 4 + w;
    const float* qp = Q + (size_t)row * NCLUST;
    float4 q0 = *(const float4*)(qp + lane * 4);
    float4 q1 = *(const float4*)(qp + 256 + lane * 4);
    float4 c0 = *(const float4*)(colsum + lane * 4);
    float4 c1 = *(const float4*)(colsum + 256 + lane * 4);
    float4 p0, p1;
    p0.x = q0.x * q0.x / c0.x; p0.y = q0.y * q0.y / c0.y;
    p0.z = q0.z * q0.z / c0.z; p0.w = q0.w * q0.w / c0.w;
    p1.x = q1.x * q1.x / c1.x; p1.y = q1.y * q1.y / c1.y;
    p1.z = q1.z * q1.z / c1.z; p1.w = q1.w * q1.w / c1.w;
    float s = p0.x + p0.y + p0.z + p0.w + p1.x + p1.y + p1.z + p1.w;
    #pragma unroll
    for (int off = 32; off; off >>= 1) s += __shfl_down(s, off);
    s = __shfl(s, 0);
    const float inv = 1.0f / s;
    p0.x *= inv; p0.y *= inv; p0.z *= inv; p0.w *= inv;
    p1.x *= inv; p1.y *= inv; p1.z *= inv; p1.w *= inv;
    float* op = P + (size_t)row * NCLUST;
    *(float4*)(op + lane * 4) = p0;
    *(float4*)(op + 256 + lane * 4) = p1;
}

extern "C" void kernel_launch(void* const* d_in, const int* in_sizes, int n_in,
                              void* d_out, int out_size, void* d_ws, size_t ws_size,
                              hipStream_t stream) {
    const float* z    = (const float*)d_in[0];
    const float* cent = (const float*)d_in[1];
    float* out = (float*)d_out;

    // workspace layout (~17.1 MiB)
    char* ws = (char*)d_ws;
    unsigned char* zb = (unsigned char*)ws;                 // 16 MiB fp8
    unsigned char* cb = (unsigned char*)(ws + 16777216);    // 1 MiB fp8
    float* zsq    = (float*)(ws + 17825792);                // 32 KiB
    float* csq    = (float*)(ws + 17858560);                // 2 KiB
    float* colsum = (float*)(ws + 17860608);                // 2 KiB

    float* Q = out;                                  // (8192, 512)
    float* P = out + (size_t)M_ROWS * NCLUST;        // (8192, 512)

    k_convert<<<dim3((M_ROWS + NCLUST) / 4), dim3(256), 0, stream>>>(
        z, cent, zb, cb, zsq, csq, colsum);

    // 256 blocks = 1/CU; 16 waves; barrier-free K-loop; fused Q epilogue
    k_gemm_fused<<<dim3(M_ROWS / BM), dim3(1024), 0, stream>>>(
        zb, cb, zsq, csq, Q, colsum);

    k_p<<<dim3(M_ROWS / 4), dim3(256), 0, stream>>>(Q, colsum, P);
}

// Round 9
// 69.209 us; speedup vs baseline: 1.0417x; 1.0417x over previous
//
#include <hip/hip_runtime.h>
#include <stdint.h>

#define M_ROWS 8192
#define NCLUST 512
#define KDIM   2048

#define BM 256
#define BN 256
#define BKB 128      // K-tile in BYTES (fp8) = 128 K-elements
#define KSPLIT 4
#define NKT (KDIM / KSPLIT / BKB)   // 4 K-tiles per block

typedef __attribute__((ext_vector_type(4))) int   i32x4;
typedef __attribute__((ext_vector_type(8))) int   i32x8;
typedef __attribute__((ext_vector_type(4))) float f32x4;
typedef __attribute__((ext_vector_type(8))) unsigned short u16x8;

// round-to-nearest-even f32 -> bf16 (bit pattern)
__device__ __forceinline__ unsigned short f2bf(float f) {
    unsigned u = __float_as_uint(f);
    u += 0x7FFFu + ((u >> 16) & 1u);
    return (unsigned short)(u >> 16);
}
__device__ __forceinline__ float bf2f(unsigned short h) {
    return __uint_as_float(((unsigned)h) << 16);
}

__device__ __forceinline__ void gload_lds16(const void* g, void* l) {
    __builtin_amdgcn_global_load_lds(
        (const __attribute__((address_space(1))) void*)g,
        (__attribute__((address_space(3))) void*)l,
        16, 0, 0);
}

// ---------------------------------------------------------------------------
// Kernel 1: f32 -> fp8 e4m3 + per-row sum of squares (from ORIGINAL f32).
// Rows 0..8191 = z, 8192..8703 = centroids. One wave per row. Zeroes colsum.
// ---------------------------------------------------------------------------
__global__ __launch_bounds__(256) void k_convert(
    const float* __restrict__ z, const float* __restrict__ cent,
    unsigned char* __restrict__ zb, unsigned char* __restrict__ cb,
    float* __restrict__ zsq, float* __restrict__ csq,
    float* __restrict__ colsum)
{
    int w = threadIdx.x >> 6, lane = threadIdx.x & 63;
    int row = blockIdx.x * 4 + w;  // 0..8703

    const float* src;
    unsigned char* dst;
    float* nrm;
    int r;
    if (row < M_ROWS) { src = z + (size_t)row * KDIM; dst = zb + (size_t)row * KDIM; nrm = zsq; r = row; }
    else              { r = row - M_ROWS; src = cent + (size_t)r * KDIM; dst = cb + (size_t)r * KDIM; nrm = csq; }

    float s = 0.f;
    #pragma unroll
    for (int it = 0; it < KDIM / 256; ++it) {
        int idx = it * 256 + lane * 4;
        float4 v = *(const float4*)(src + idx);
        s += v.x * v.x + v.y * v.y + v.z * v.z + v.w * v.w;
        int p = __builtin_amdgcn_cvt_pk_fp8_f32(v.x, v.y, 0, 0);   // bytes 0,1
        p     = __builtin_amdgcn_cvt_pk_fp8_f32(v.z, v.w, p, 1);   // bytes 2,3
        *(int*)(dst + idx) = p;
    }
    #pragma unroll
    for (int off = 32; off; off >>= 1) s += __shfl_down(s, off);
    if (lane == 0) nrm[r] = s;

    if (blockIdx.x == 0) {
        colsum[threadIdx.x] = 0.f;
        colsum[threadIdx.x + 256] = 0.f;
    }
}

// ---------------------------------------------------------------------------
// Kernel 2: split-K fp8 MFMA partial GEMM -- faithful m201-style 8-phase
// schedule at the template's exact regime: 256x256 tile, 512 threads
// (8 waves, 2Mx4N, wave-out 128x64), LDS 128 KiB, 1 block/CU.
// K-tile = 128 fp8 elements = 128 B/row (byte-identical to BK=64 bf16).
//
// Per K-tile: 4 phases (quadrant q = wave rows 2q,2q+1 x all 4 col-frags):
//   P0:   issue 2 gloads (tile t+1) ; s_waitcnt vmcnt(2)  [never 0 mid-loop;
//         retires tile t's 8 loads, keeps the 2 new in flight] ; s_barrier ;
//         ds_read B-frags(8xb128)+A-frags(4xb128) ; lgkmcnt(0) ; sched_barrier;
//         setprio(1) ; 8 MFMA ; setprio(0) ; s_barrier
//   P1-3: issue 2 gloads ; ds_read A-frags(4xb128) ; s_barrier ; lgkmcnt(0) ;
//         sched_barrier ; setprio(1) ; 8 MFMA ; setprio(0) ; s_barrier
// Hazard audit: gloads write buf[t^1], last read by tile t-1 P3 (sealed by
// its closing barrier); buf[t] validity = per-wave vmcnt + barrier at P0.
//
// LDS swizzle (both-sides involution, proven R3-R8): row = 8 slots of 16B;
// physical slot p at row r holds logical slot p ^ (r&7); pre-swizzled global
// source (linear LDS dest), same XOR on ds_read.
// ---------------------------------------------------------------------------
__global__ __launch_bounds__(512, 2) void k_gemm_part(
    const unsigned char* __restrict__ zb, const unsigned char* __restrict__ cb,
    unsigned short* __restrict__ parts)   // [KSPLIT][M_ROWS][NCLUST] bf16
{
    __shared__ unsigned char As[2][BM * BKB];   // 32 KiB x2
    __shared__ unsigned char Bs[2][BN * BKB];   // 32 KiB x2

    const int wgid = blockIdx.x;          // 0..255
    const int by   = wgid & 31;           // M-tile 0..31
    const int rest = wgid >> 5;           // 0..7
    const int bx   = rest & 1;            // N-tile 0..1
    const int bz   = rest >> 1;           // K-chunk 0..3
    const int bRow = by * BM;
    const int bCol = bx * BN;
    const size_t kb0 = (size_t)bz * (KDIM / KSPLIT);   // byte offset in K

    const int tid  = threadIdx.x;
    const int w    = tid >> 6, lane = tid & 63;
    const int wrow = w >> 2, wcol = w & 3;   // 2x4 wave grid

    f32x4 acc[8][4] = {};

    // staging: 1 gload = 1 KiB = 8 rows x 128B.  8 gloads/wave/tile, issued
    // 2 per phase (A-group + B-group w*4+q).  srow = lane>>3; physical slot
    // = lane&7; source logical slot = (lane&7) ^ srow.
    const int srow = lane >> 3;
    const int scol = ((lane & 7) ^ srow) * 16;
    const unsigned char* gA = zb + (size_t)(bRow + srow) * KDIM + kb0 + scol;
    const unsigned char* gB = cb + (size_t)(bCol + srow) * KDIM + kb0 + scol;

    const int arowb = wrow * 128 + (lane & 15);
    const int bcolb = wcol * 64 + (lane & 15);
    const int s     = lane >> 4;       // K 32-byte block 0..3
    const int r7    = lane & 7;        // row&7 for all fragment rows
    const int sc    = 0x7F7F7F7F;      // e8m0 scale 127 = 2^0 per byte

    // prologue: stage tile 0 fully (8 gloads)
    #pragma unroll
    for (int q = 0; q < 4; ++q) {
        const int g = w * 4 + q;
        gload_lds16(gA + (size_t)(g * 8) * KDIM, &As[0][g * 1024]);
        gload_lds16(gB + (size_t)(g * 8) * KDIM, &Bs[0][g * 1024]);
    }

    #pragma unroll
    for (int t = 0; t < NKT; ++t) {
        const int buf = t & 1;
        const unsigned char* A0 = &As[buf][0];
        const unsigned char* B0 = &Bs[buf][0];
        i32x8 bfr[4];

        #pragma unroll
        for (int q = 0; q < 4; ++q) {
            // issue 2 gloads of tile t+1 (group w*4+q)
            if (t + 1 < NKT) {
                const int g  = w * 4 + q;
                const int kb = (t + 1) * BKB;
                gload_lds16(gA + (size_t)(g * 8) * KDIM + kb, &As[buf ^ 1][g * 1024]);
                gload_lds16(gB + (size_t)(g * 8) * KDIM + kb, &Bs[buf ^ 1][g * 1024]);
            }

            i32x8 af[2];
            if (q == 0) {
                // counted vmcnt: allow only the 2 just-issued to remain
                if (t + 1 < NKT) asm volatile("s_waitcnt vmcnt(2)" ::: "memory");
                else             asm volatile("s_waitcnt vmcnt(0)" ::: "memory");
                __builtin_amdgcn_s_barrier();      // buf[t] now valid for all
                // B-frags for the whole tile (8 x b128) + A-frags q0 (4 x b128)
                #pragma unroll
                for (int j = 0; j < 4; ++j) {
                    const int row = bcolb + j * 16;
                    const i32x4 lo = *(const i32x4*)&B0[row * BKB + ((2 * s) ^ r7) * 16];
                    const i32x4 hi = *(const i32x4*)&B0[row * BKB + ((2 * s + 1) ^ r7) * 16];
                    bfr[j][0] = lo[0]; bfr[j][1] = lo[1]; bfr[j][2] = lo[2]; bfr[j][3] = lo[3];
                    bfr[j][4] = hi[0]; bfr[j][5] = hi[1]; bfr[j][6] = hi[2]; bfr[j][7] = hi[3];
                }
                #pragma unroll
                for (int ii = 0; ii < 2; ++ii) {
                    const int row = arowb + ii * 16;
                    const i32x4 lo = *(const i32x4*)&A0[row * BKB + ((2 * s) ^ r7) * 16];
                    const i32x4 hi = *(const i32x4*)&A0[row * BKB + ((2 * s + 1) ^ r7) * 16];
                    af[ii][0] = lo[0]; af[ii][1] = lo[1]; af[ii][2] = lo[2]; af[ii][3] = lo[3];
                    af[ii][4] = hi[0]; af[ii][5] = hi[1]; af[ii][6] = hi[2]; af[ii][7] = hi[3];
                }
            } else {
                // ds_read before the barrier (overlap with other waves' loads)
                #pragma unroll
                for (int ii = 0; ii < 2; ++ii) {
                    const int row = arowb + (q * 2 + ii) * 16;
                    const i32x4 lo = *(const i32x4*)&A0[row * BKB + ((2 * s) ^ r7) * 16];
                    const i32x4 hi = *(const i32x4*)&A0[row * BKB + ((2 * s + 1) ^ r7) * 16];
                    af[ii][0] = lo[0]; af[ii][1] = lo[1]; af[ii][2] = lo[2]; af[ii][3] = lo[3];
                    af[ii][4] = hi[0]; af[ii][5] = hi[1]; af[ii][6] = hi[2]; af[ii][7] = hi[3];
                }
                __builtin_amdgcn_s_barrier();
            }

            asm volatile("s_waitcnt lgkmcnt(0)" ::: "memory");
            __builtin_amdgcn_sched_barrier(0);      // rule #18
            __builtin_amdgcn_s_setprio(1);
            #pragma unroll
            for (int ii = 0; ii < 2; ++ii)
                #pragma unroll
                for (int j = 0; j < 4; ++j)
                    acc[q * 2 + ii][j] = __builtin_amdgcn_mfma_scale_f32_16x16x128_f8f6f4(
                        af[ii], bfr[j], acc[q * 2 + ii][j], 0, 0, 0, sc, 0, sc);
            __builtin_amdgcn_s_setprio(0);
            __builtin_amdgcn_sched_barrier(0);
            __builtin_amdgcn_s_barrier();
        }
    }

    unsigned short* dst = parts + (size_t)bz * M_ROWS * NCLUST;
    // C/D frag mapping: col=lane&15, row=(lane>>4)*4+reg (shape-determined)
    const int col0 = bCol + wcol * 64 + (lane & 15);
    const int row0 = bRow + wrow * 128 + (lane >> 4) * 4;
    #pragma unroll
    for (int j = 0; j < 4; ++j) {
        const int col = col0 + j * 16;
        #pragma unroll
        for (int i = 0; i < 8; ++i)
            #pragma unroll
            for (int r = 0; r < 4; ++r)
                dst[(size_t)(row0 + i * 16 + r) * NCLUST + col] = f2bf(acc[i][j][r]);
    }
}

// ---------------------------------------------------------------------------
// Kernel 3: combine 4 bf16 partials -> Q = 1/(1+sqrt(max(zsq+csq-2*cross,0))),
// row-normalize, column-sum (LDS reduce -> atomics).  32 rows/block.
// ---------------------------------------------------------------------------
__global__ __launch_bounds__(256) void k_q_norm(
    const unsigned short* __restrict__ parts,
    const float* __restrict__ zsq, const float* __restrict__ csq,
    float* __restrict__ Q, float* __restrict__ colsum)
{
    __shared__ float red[4][NCLUST];
    const int tid = threadIdx.x, w = tid >> 6, lane = tid & 63;
    const size_t PSTR = (size_t)M_ROWS * NCLUST;
    float ca[8] = {0, 0, 0, 0, 0, 0, 0, 0};
    const int rbase = blockIdx.x * 32;

    float cs[8];
    {
        float4 c0 = *(const float4*)(csq + lane * 8);
        float4 c1 = *(const float4*)(csq + lane * 8 + 4);
        cs[0] = c0.x; cs[1] = c0.y; cs[2] = c0.z; cs[3] = c0.w;
        cs[4] = c1.x; cs[5] = c1.y; cs[6] = c1.z; cs[7] = c1.w;
    }

    for (int rr = 0; rr < 8; ++rr) {
        const int row = rbase + w + rr * 4;
        const size_t off = (size_t)row * NCLUST + lane * 8;
        float x[8] = {0, 0, 0, 0, 0, 0, 0, 0};
        #pragma unroll
        for (int p = 0; p < KSPLIT; ++p) {
            u16x8 v = *(const u16x8*)(parts + p * PSTR + off);
            #pragma unroll
            for (int k = 0; k < 8; ++k) x[k] += bf2f(v[k]);
        }
        const float zr = zsq[row];
        float q[8];
        float sum = 0.f;
        #pragma unroll
        for (int k = 0; k < 8; ++k) {
            q[k] = 1.0f / (1.0f + sqrtf(fmaxf(zr + cs[k] - 2.0f * x[k], 0.0f)));
            sum += q[k];
        }
        #pragma unroll
        for (int o = 32; o; o >>= 1) sum += __shfl_down(sum, o);
        sum = __shfl(sum, 0);
        const float inv = 1.0f / sum;
        float4 q0, q1;
        q0.x = q[0] * inv; q0.y = q[1] * inv; q0.z = q[2] * inv; q0.w = q[3] * inv;
        q1.x = q[4] * inv; q1.y = q[5] * inv; q1.z = q[6] * inv; q1.w = q[7] * inv;
        *(float4*)(Q + off)     = q0;
        *(float4*)(Q + off + 4) = q1;
        ca[0] += q0.x; ca[1] += q0.y; ca[2] += q0.z; ca[3] += q0.w;
        ca[4] += q1.x; ca[5] += q1.y; ca[6] += q1.z; ca[7] += q1.w;
    }
    #pragma unroll
    for (int c = 0; c < 8; ++c) red[w][lane * 8 + c] = ca[c];
    __syncthreads();
    const float t0 = red[0][tid] + red[1][tid] + red[2][tid] + red[3][tid];
    const float t1 = red[0][tid + 256] + red[1][tid + 256] + red[2][tid + 256] + red[3][tid + 256];
    atomicAdd(&colsum[tid], t0);
    atomicAdd(&colsum[tid + 256], t1);
}

// ---------------------------------------------------------------------------
// Kernel 4: P = rownorm(Q^2 / colsum). One wave per row.
// ---------------------------------------------------------------------------
__global__ __launch_bounds__(256) void k_p(
    const float* __restrict__ Q, const float* __restrict__ colsum,
    float* __restrict__ P)
{
    const int w = threadIdx.x >> 6, lane = threadIdx.x & 63;
    const int row = blockIdx.x * 4 + w;
    const float* qp = Q + (size_t)row * NCLUST;
    float4 q0 = *(const float4*)(qp + lane * 4);
    float4 q1 = *(const float4*)(qp + 256 + lane * 4);
    float4 c0 = *(const float4*)(colsum + lane * 4);
    float4 c1 = *(const float4*)(colsum + 256 + lane * 4);
    float4 p0, p1;
    p0.x = q0.x * q0.x / c0.x; p0.y = q0.y * q0.y / c0.y;
    p0.z = q0.z * q0.z / c0.z; p0.w = q0.w * q0.w / c0.w;
    p1.x = q1.x * q1.x / c1.x; p1.y = q1.y * q1.y / c1.y;
    p1.z = q1.z * q1.z / c1.z; p1.w = q1.w * q1.w / c1.w;
    float s = p0.x + p0.y + p0.z + p0.w + p1.x + p1.y + p1.z + p1.w;
    #pragma unroll
    for (int off = 32; off; off >>= 1) s += __shfl_down(s, off);
    s = __shfl(s, 0);
    const float inv = 1.0f / s;
    p0.x *= inv; p0.y *= inv; p0.z *= inv; p0.w *= inv;
    p1.x *= inv; p1.y *= inv; p1.z *= inv; p1.w *= inv;
    float* op = P + (size_t)row * NCLUST;
    *(float4*)(op + lane * 4) = p0;
    *(float4*)(op + 256 + lane * 4) = p1;
}

extern "C" void kernel_launch(void* const* d_in, const int* in_sizes, int n_in,
                              void* d_out, int out_size, void* d_ws, size_t ws_size,
                              hipStream_t stream) {
    const float* z    = (const float*)d_in[0];
    const float* cent = (const float*)d_in[1];
    float* out = (float*)d_out;

    // workspace layout (~51 MiB; ws >= 69 MiB proven empirically in R3)
    char* ws = (char*)d_ws;
    unsigned char* zb = (unsigned char*)ws;                 // 16 MiB fp8
    unsigned char* cb = (unsigned char*)(ws + 16777216);    // 1 MiB fp8
    float* zsq    = (float*)(ws + 17825792);                // 32 KiB
    float* csq    = (float*)(ws + 17858560);                // 2 KiB
    float* colsum = (float*)(ws + 17860608);                // 2 KiB
    unsigned short* parts = (unsigned short*)(ws + 18874368); // 4 x 8 MiB bf16

    float* Q = out;                                  // (8192, 512)
    float* P = out + (size_t)M_ROWS * NCLUST;        // (8192, 512)

    k_convert<<<dim3((M_ROWS + NCLUST) / 4), dim3(256), 0, stream>>>(
        z, cent, zb, cb, zsq, csq, colsum);

    // 256 blocks = 1/CU; 8 waves; 8-phase counted-vmcnt schedule
    k_gemm_part<<<dim3(256), dim3(512), 0, stream>>>(zb, cb, parts);

    k_q_norm<<<dim3(M_ROWS / 32), dim3(256), 0, stream>>>(
        parts, zsq, csq, Q, colsum);

    k_p<<<dim3(M_ROWS / 4), dim3(256), 0, stream>>>(Q, colsum, P);
}

// Round 10
// 55.935 us; speedup vs baseline: 1.2889x; 1.2373x over previous
//
#include <hip/hip_runtime.h>
#include <stdint.h>

#define M_ROWS 8192
#define NCLUST 512
#define KDIM   2048

#define BM 128
#define BN 128
#define BKB 128      // K-step in BYTES (fp8) = 128 K-elements
#define KSPLIT 2
#define NKT (KDIM / KSPLIT / BKB)   // 8 K-steps per block

typedef __attribute__((ext_vector_type(4))) int   i32x4;
typedef __attribute__((ext_vector_type(8))) int   i32x8;
typedef __attribute__((ext_vector_type(4))) float f32x4;
typedef __attribute__((ext_vector_type(8))) unsigned short u16x8;

// round-to-nearest-even f32 -> bf16 (bit pattern)
__device__ __forceinline__ unsigned short f2bf(float f) {
    unsigned u = __float_as_uint(f);
    u += 0x7FFFu + ((u >> 16) & 1u);
    return (unsigned short)(u >> 16);
}
__device__ __forceinline__ float bf2f(unsigned short h) {
    return __uint_as_float(((unsigned)h) << 16);
}

__device__ __forceinline__ void gload_lds16(const void* g, void* l) {
    __builtin_amdgcn_global_load_lds(
        (const __attribute__((address_space(1))) void*)g,
        (__attribute__((address_space(3))) void*)l,
        16, 0, 0);
}

// ---------------------------------------------------------------------------
// Kernel 1: f32 -> fp8 e4m3 + per-row sum of squares (from ORIGINAL f32).
// Rows 0..8191 = z, 8192..8703 = centroids. One wave per row. Zeroes colsum.
// ---------------------------------------------------------------------------
__global__ __launch_bounds__(256) void k_convert(
    const float* __restrict__ z, const float* __restrict__ cent,
    unsigned char* __restrict__ zb, unsigned char* __restrict__ cb,
    float* __restrict__ zsq, float* __restrict__ csq,
    float* __restrict__ colsum)
{
    int w = threadIdx.x >> 6, lane = threadIdx.x & 63;
    int row = blockIdx.x * 4 + w;  // 0..8703

    const float* src;
    unsigned char* dst;
    float* nrm;
    int r;
    if (row < M_ROWS) { src = z + (size_t)row * KDIM; dst = zb + (size_t)row * KDIM; nrm = zsq; r = row; }
    else              { r = row - M_ROWS; src = cent + (size_t)r * KDIM; dst = cb + (size_t)r * KDIM; nrm = csq; }

    float s = 0.f;
    #pragma unroll
    for (int it = 0; it < KDIM / 256; ++it) {
        int idx = it * 256 + lane * 4;
        float4 v = *(const float4*)(src + idx);
        s += v.x * v.x + v.y * v.y + v.z * v.z + v.w * v.w;
        int p = __builtin_amdgcn_cvt_pk_fp8_f32(v.x, v.y, 0, 0);   // bytes 0,1
        p     = __builtin_amdgcn_cvt_pk_fp8_f32(v.z, v.w, p, 1);   // bytes 2,3
        *(int*)(dst + idx) = p;
    }
    #pragma unroll
    for (int off = 32; off; off >>= 1) s += __shfl_down(s, off);
    if (lane == 0) nrm[r] = s;

    if (blockIdx.x == 0) {
        colsum[threadIdx.x] = 0.f;
        colsum[threadIdx.x + 256] = 0.f;
    }
}

// ---------------------------------------------------------------------------
// Kernel 2: split-K fp8 MFMA partial GEMM (R5's proven 2-phase skeleton) +
// XCD-aware block decode + bf16 partial output.
// 128x128 tile, K-step 128 fp8 elements, 4 waves (2x2, acc[4][4]), KSPLIT=2,
// grid 512 -> 2 blocks/CU (LDS 64 KiB).
//
// XCD decode: wgid = (by&7) + 8*(bx + 4*bz + 8*(by>>3)); with round-robin
// wgid%8 -> XCD, all 8 blocks sharing an A-panel (4 bx x 2 bz of one by)
// land on ONE XCD -> A staged into one L2 instead of 8 (cuts HBM over-fetch
// ~2x; T1 mechanism).  Bijective over 512.
//
// LDS swizzle (both-sides involution, proven R3-R5): row = 8 slots of 16B;
// physical slot p at row r holds logical slot p ^ (r&7); pre-swizzled global
// source (linear LDS dest, as global_load_lds requires), same XOR on ds_read.
// ---------------------------------------------------------------------------
__global__ __launch_bounds__(512) void k_gemm_part(
    const unsigned char* __restrict__ zb, const unsigned char* __restrict__ cb,
    unsigned short* __restrict__ parts)   // [KSPLIT][M_ROWS][NCLUST] bf16
{
    __shared__ unsigned char As[2][BM * BKB];   // 16 KiB x2
    __shared__ unsigned char Bs[2][BN * BKB];   // 16 KiB x2

    // XCD-aware decode (bijective): by&7 = wgid&7
    const int wgid = blockIdx.x;            // 0..511
    const int inner = wgid >> 3;            // 0..63
    const int bx  = inner & 3;              // N-tile 0..3
    const int bz  = (inner >> 2) & 1;       // K-chunk 0..1
    const int by  = ((inner >> 3) << 3) | (wgid & 7);   // M-tile 0..63
    const int bRow = by * BM;
    const int bCol = bx * BN;
    const size_t kb0 = (size_t)bz * (KDIM / KSPLIT);    // byte offset in K

    const int tid  = threadIdx.x & 255;     // use 256 of... (4 waves)
    const int w    = (threadIdx.x >> 6) & 3, lane = threadIdx.x & 63;
    const int wr   = w >> 1,  wc   = w & 1;

    // NOTE: launched with 256 threads (4 waves); block dim passed as 256.
    f32x4 acc[4][4] = {};

    // staging: each wave-issue covers 8 rows x 128B (1 KiB); 16 issues per
    // matrix per K-step (4 per wave).  srow = lane>>3 (0..7); physical 16B
    // slot = lane&7; source logical slot = (lane&7) ^ srow.
    const int srow = lane >> 3;
    const int scol = ((lane & 7) ^ srow) * 16;
    const unsigned char* gA = zb + (size_t)(bRow + srow) * KDIM + kb0 + scol;
    const unsigned char* gB = cb + (size_t)(bCol + srow) * KDIM + kb0 + scol;

    auto stage = [&](int buf, int kt) {
        const int kb = kt * BKB;
        #pragma unroll
        for (int j = 0; j < 4; ++j) {
            const int g = w * 4 + j;   // 8-row group 0..15
            gload_lds16(gA + (size_t)(g * 8) * KDIM + kb, &As[buf][g * 1024]);
            gload_lds16(gB + (size_t)(g * 8) * KDIM + kb, &Bs[buf][g * 1024]);
        }
    };

    const int arowb = wr * 64 + (lane & 15);
    const int bcolb = wc * 64 + (lane & 15);
    const int s     = lane >> 4;       // K 32-byte block 0..3
    const int r7    = lane & 7;        // row&7 for all fragment rows
    const int sc    = 0x7F7F7F7F;      // e8m0 scale 127 = 2^0 per byte

    auto compute = [&](int buf) {
        const unsigned char* A0 = &As[buf][0];
        const unsigned char* B0 = &Bs[buf][0];
        i32x8 af[4], bfr[4];
        #pragma unroll
        for (int i = 0; i < 4; ++i) {
            const int row = arowb + i * 16;
            const i32x4 lo = *(const i32x4*)&A0[row * BKB + ((2 * s) ^ r7) * 16];
            const i32x4 hi = *(const i32x4*)&A0[row * BKB + ((2 * s + 1) ^ r7) * 16];
            af[i][0] = lo[0]; af[i][1] = lo[1]; af[i][2] = lo[2]; af[i][3] = lo[3];
            af[i][4] = hi[0]; af[i][5] = hi[1]; af[i][6] = hi[2]; af[i][7] = hi[3];
        }
        #pragma unroll
        for (int j = 0; j < 4; ++j) {
            const int row = bcolb + j * 16;
            const i32x4 lo = *(const i32x4*)&B0[row * BKB + ((2 * s) ^ r7) * 16];
            const i32x4 hi = *(const i32x4*)&B0[row * BKB + ((2 * s + 1) ^ r7) * 16];
            bfr[j][0] = lo[0]; bfr[j][1] = lo[1]; bfr[j][2] = lo[2]; bfr[j][3] = lo[3];
            bfr[j][4] = hi[0]; bfr[j][5] = hi[1]; bfr[j][6] = hi[2]; bfr[j][7] = hi[3];
        }
        #pragma unroll
        for (int i = 0; i < 4; ++i)
            #pragma unroll
            for (int j = 0; j < 4; ++j)
                acc[i][j] = __builtin_amdgcn_mfma_scale_f32_16x16x128_f8f6f4(
                    af[i], bfr[j], acc[i][j], 0, 0, 0, sc, 0, sc);
    };

    stage(0, 0);
    __syncthreads();
    int buf = 0;
    for (int kt = 0; kt < NKT - 1; ++kt) {
        stage(buf ^ 1, kt + 1);
        compute(buf);
        __syncthreads();
        buf ^= 1;
    }
    compute(buf);

    unsigned short* dst = parts + (size_t)bz * M_ROWS * NCLUST;
    // C/D frag mapping: col=lane&15, row=(lane>>4)*4+reg (shape-determined)
    const int col0 = bCol + wc * 64 + (lane & 15);
    const int row0 = bRow + wr * 64 + (lane >> 4) * 4;
    #pragma unroll
    for (int j = 0; j < 4; ++j) {
        const int col = col0 + j * 16;
        #pragma unroll
        for (int i = 0; i < 4; ++i)
            #pragma unroll
            for (int r = 0; r < 4; ++r)
                dst[(size_t)(row0 + i * 16 + r) * NCLUST + col] = f2bf(acc[i][j][r]);
    }
    (void)tid;
}

// ---------------------------------------------------------------------------
// Kernel 3: combine 2 bf16 partials -> Q = 1/(1+sqrt(max(zsq+csq-2*cross,0))),
// row-normalize, column-sum (LDS reduce -> atomics).  32 rows/block, one
// wave per row, lane covers cols lane*8..+7.
// ---------------------------------------------------------------------------
__global__ __launch_bounds__(256) void k_q_norm(
    const unsigned short* __restrict__ parts,
    const float* __restrict__ zsq, const float* __restrict__ csq,
    float* __restrict__ Q, float* __restrict__ colsum)
{
    __shared__ float red[4][NCLUST];
    const int tid = threadIdx.x, w = tid >> 6, lane = tid & 63;
    const size_t PSTR = (size_t)M_ROWS * NCLUST;
    float ca[8] = {0, 0, 0, 0, 0, 0, 0, 0};
    const int rbase = blockIdx.x * 32;

    float cs[8];
    {
        float4 c0 = *(const float4*)(csq + lane * 8);
        float4 c1 = *(const float4*)(csq + lane * 8 + 4);
        cs[0] = c0.x; cs[1] = c0.y; cs[2] = c0.z; cs[3] = c0.w;
        cs[4] = c1.x; cs[5] = c1.y; cs[6] = c1.z; cs[7] = c1.w;
    }

    for (int rr = 0; rr < 8; ++rr) {
        const int row = rbase + w + rr * 4;
        const size_t off = (size_t)row * NCLUST + lane * 8;
        float x[8];
        {
            u16x8 v0 = *(const u16x8*)(parts + off);
            u16x8 v1 = *(const u16x8*)(parts + PSTR + off);
            #pragma unroll
            for (int k = 0; k < 8; ++k) x[k] = bf2f(v0[k]) + bf2f(v1[k]);
        }
        const float zr = zsq[row];
        float q[8];
        float sum = 0.f;
        #pragma unroll
        for (int k = 0; k < 8; ++k) {
            q[k] = 1.0f / (1.0f + sqrtf(fmaxf(zr + cs[k] - 2.0f * x[k], 0.0f)));
            sum += q[k];
        }
        #pragma unroll
        for (int o = 32; o; o >>= 1) sum += __shfl_down(sum, o);
        sum = __shfl(sum, 0);
        const float inv = 1.0f / sum;
        float4 q0, q1;
        q0.x = q[0] * inv; q0.y = q[1] * inv; q0.z = q[2] * inv; q0.w = q[3] * inv;
        q1.x = q[4] * inv; q1.y = q[5] * inv; q1.z = q[6] * inv; q1.w = q[7] * inv;
        *(float4*)(Q + off)     = q0;
        *(float4*)(Q + off + 4) = q1;
        ca[0] += q0.x; ca[1] += q0.y; ca[2] += q0.z; ca[3] += q0.w;
        ca[4] += q1.x; ca[5] += q1.y; ca[6] += q1.z; ca[7] += q1.w;
    }
    #pragma unroll
    for (int c = 0; c < 8; ++c) red[w][lane * 8 + c] = ca[c];
    __syncthreads();
    const float t0 = red[0][tid] + red[1][tid] + red[2][tid] + red[3][tid];
    const float t1 = red[0][tid + 256] + red[1][tid + 256] + red[2][tid + 256] + red[3][tid + 256];
    atomicAdd(&colsum[tid], t0);
    atomicAdd(&colsum[tid + 256], t1);
}

// ---------------------------------------------------------------------------
// Kernel 4: P = rownorm(Q^2 / colsum). One wave per row.
// ---------------------------------------------------------------------------
__global__ __launch_bounds__(256) void k_p(
    const float* __restrict__ Q, const float* __restrict__ colsum,
    float* __restrict__ P)
{
    const int w = threadIdx.x >> 6, lane = threadIdx.x & 63;
    const int row = blockIdx.x * 4 + w;
    const float* qp = Q + (size_t)row * NCLUST;
    float4 q0 = *(const float4*)(qp + lane * 4);
    float4 q1 = *(const float4*)(qp + 256 + lane * 4);
    float4 c0 = *(const float4*)(colsum + lane * 4);
    float4 c1 = *(const float4*)(colsum + 256 + lane * 4);
    float4 p0, p1;
    p0.x = q0.x * q0.x / c0.x; p0.y = q0.y * q0.y / c0.y;
    p0.z = q0.z * q0.z / c0.z; p0.w = q0.w * q0.w / c0.w;
    p1.x = q1.x * q1.x / c1.x; p1.y = q1.y * q1.y / c1.y;
    p1.z = q1.z * q1.z / c1.z; p1.w = q1.w * q1.w / c1.w;
    float s = p0.x + p0.y + p0.z + p0.w + p1.x + p1.y + p1.z + p1.w;
    #pragma unroll
    for (int off = 32; off; off >>= 1) s += __shfl_down(s, off);
    s = __shfl(s, 0);
    const float inv = 1.0f / s;
    p0.x *= inv; p0.y *= inv; p0.z *= inv; p0.w *= inv;
    p1.x *= inv; p1.y *= inv; p1.z *= inv; p1.w *= inv;
    float* op = P + (size_t)row * NCLUST;
    *(float4*)(op + lane * 4) = p0;
    *(float4*)(op + 256 + lane * 4) = p1;
}

extern "C" void kernel_launch(void* const* d_in, const int* in_sizes, int n_in,
                              void* d_out, int out_size, void* d_ws, size_t ws_size,
                              hipStream_t stream) {
    const float* z    = (const float*)d_in[0];
    const float* cent = (const float*)d_in[1];
    float* out = (float*)d_out;

    // workspace layout (~35 MiB; ws >= 69 MiB proven empirically in R3)
    char* ws = (char*)d_ws;
    unsigned char* zb = (unsigned char*)ws;                 // 16 MiB fp8
    unsigned char* cb = (unsigned char*)(ws + 16777216);    // 1 MiB fp8
    float* zsq    = (float*)(ws + 17825792);                // 32 KiB
    float* csq    = (float*)(ws + 17858560);                // 2 KiB
    float* colsum = (float*)(ws + 17860608);                // 2 KiB
    unsigned short* parts = (unsigned short*)(ws + 18874368); // 2 x 8 MiB bf16

    float* Q = out;                                  // (8192, 512)
    float* P = out + (size_t)M_ROWS * NCLUST;        // (8192, 512)

    k_convert<<<dim3((M_ROWS + NCLUST) / 4), dim3(256), 0, stream>>>(
        z, cent, zb, cb, zsq, csq, colsum);

    // grid 512 (XCD-aware decode inside) -> 2 blocks/CU, 4 waves each
    k_gemm_part<<<dim3(512), dim3(256), 0, stream>>>(zb, cb, parts);

    k_q_norm<<<dim3(M_ROWS / 32), dim3(256), 0, stream>>>(
        parts, zsq, csq, Q, colsum);

    k_p<<<dim3(M_ROWS / 4), dim3(256), 0, stream>>>(Q, colsum, P);
}